// Round 7
// baseline (193.049 us; speedup 1.0000x reference)
//
#include <hip/hip_runtime.h>

// GridSamplePScan: out[b,t,c] = sum_{k<=t} bilinear(images[b,k,c], wrap(base + cum_t - cum_k))
// B=4, L=32, C=16, H=W=64, fp32 in/out.
//
// R6: LDS-staged gather, race-free version.
//   R3-R5 failed (absmax 1.31): raw s_barrier is not an IR memory fence, so
//   hipcc could move ds_reads across it -> cross-wave race with
//   global_load_lds staging. Fix: T14 reg-staging with full __syncthreads()
//   fences (no novel sync semantics):
//     per k-iter: sync(A) -> ds_write frame k (from regs) -> sync(B)
//                 -> issue global loads of frame k+1 into regs (latency hides
//                    under compute) -> bilinear-gather frame k from LDS.
//   Single 64KB static LDS buffer; 256 blocks x 1024 thr = 1 block/CU, zero
//   tail; triangle pairing (t, 31-t) keeps every block at 33 k-iterations.
//   px math is bit-identical to the R2 kernel (passed, absmax 0.0625).

constexpr int BN = 4, LN = 32, CN = 16, HWn = 4096;
constexpr int FRAME = CN * HWn;
constexpr size_t TIMG_BYTES = (size_t)BN * LN * HWn * CN * 2;  // 16 MB fp16
constexpr size_t CUM_BYTES  = (size_t)BN * LN * HWn * 2 * 4;   // 4 MB f32

// ---------------------------------------------------------------------------
// images fp32 [B,L,C,H,W] -> fp16 [B*L][chhalf(2)][4096 px][8ch] (16B cells)
// ---------------------------------------------------------------------------
__global__ __launch_bounds__(256) void prep_timg(
        const float* __restrict__ img, float4* __restrict__ timg) {
    const int bi = blockIdx.x, tile = bi & 15, f = bi >> 4;   // f = b*L + l
    const int p = (tile << 8) + threadIdx.x;
    const float* src = img + (size_t)f * FRAME + p;
#pragma unroll
    for (int g = 0; g < 2; ++g) {
        union { float4 f4; _Float16 h[8]; } cell;
#pragma unroll
        for (int j = 0; j < 8; ++j)
            cell.h[j] = (_Float16)src[(g * 8 + j) * HWn];     // coalesced
        timg[((size_t)f * 2 + g) * HWn + p] = cell.f4;        // 16B/lane
    }
}

// ---------------------------------------------------------------------------
__global__ __launch_bounds__(256) void prep_cum(
        const float* __restrict__ flows, float2* __restrict__ cum) {
    const int b = blockIdx.x >> 4;
    const int p = ((blockIdx.x & 15) << 8) + threadIdx.x;
    const float* fl = flows + (size_t)b * (LN * 2 * HWn) + p;
    float cx = 0.f, cy = 0.f;
    for (int l = 0; l < LN; ++l) {              // ascending == jnp.cumsum
        cx += fl[(2 * l) * HWn];
        cy += fl[(2 * l + 1) * HWn];
        cum[(size_t)(b * LN + l) * HWn + p] = make_float2(cx, cy);
    }
}

// ---------------------------------------------------------------------------
// Bilinear sample of one pixel from the LDS-resident 8-channel frame.
// Math is bit-identical to the reference (and to the passing R2 kernel).
// ---------------------------------------------------------------------------
__device__ __forceinline__ void px_step(const float4* __restrict__ fr,
                                        float2 ct, float2 ck,
                                        float bx, float by,
                                        float* __restrict__ acc) {
    float vx = (bx + (ct.x - ck.x)) + 1.0f;     // (base + rel) + 1, ref order
    float vy = (by + (ct.y - ck.y)) + 1.0f;
    float mx = vx - 2.0f * floorf(vx * 0.5f);   // == jnp.mod(v,2) bitwise
    float my = vy - 2.0f * floorf(vy * 0.5f);
    float ix = ((mx - 1.0f) + 1.0f) * 32.0f - 0.5f;  // keep ref's -1/+1 trip
    float iy = ((my - 1.0f) + 1.0f) * 32.0f - 0.5f;
    float xf = floorf(ix), yf = floorf(iy);
    int x0 = (int)xf, y0 = (int)yf;             // [-1, 63]
    float wx1 = ix - xf, wy1 = iy - yf;
    float wx0 = 1.0f - wx1, wy0 = 1.0f - wy1;
    wx0 = (x0 >= 0) ? wx0 : 0.0f;               // zero-pad outside image
    wx1 = (x0 <= 62) ? wx1 : 0.0f;
    wy0 = (y0 >= 0) ? wy0 : 0.0f;
    wy1 = (y0 <= 62) ? wy1 : 0.0f;
    const int x0c = max(x0, 0), y0c = max(y0, 0);
    const int x1c = min(x0 + 1, 63), y1c = min(y0 + 1, 63);
    const float w00 = wx0 * wy0, w10 = wx1 * wy0;
    const float w01 = wx0 * wy1, w11 = wx1 * wy1;
    union { float4 f4; _Float16 h[8]; } g00, g10, g01, g11;
    g00.f4 = fr[(y0c << 6) + x0c];              // ds_read_b128
    g10.f4 = fr[(y0c << 6) + x1c];
    g01.f4 = fr[(y1c << 6) + x0c];
    g11.f4 = fr[(y1c << 6) + x1c];
#pragma unroll
    for (int c = 0; c < 8; ++c)                 // v_fma_mix_f32: f32 accum
        acc[c] += ((w00 * (float)g00.h[c] + w10 * (float)g10.h[c])
                   + w01 * (float)g01.h[c]) + w11 * (float)g11.h[c];
}

// ---------------------------------------------------------------------------
__global__ __launch_bounds__(1024) void gsps_lds(
        const float2* __restrict__ cum,
        const float4* __restrict__ timg4,
        float* __restrict__ out) {
    __shared__ float4 sbuf[4096];               // 64 KB, single buffer
    const int bid = blockIdx.x;                 // 256 blocks
    const int xs  = bid & 7;                    // XCD slot (round-robin)
    const int b   = xs >> 1;                    // batch pinned to XCD pair
    const int pxh = xs & 1;
    const int seq = bid >> 3;
    const int pair = seq & 15;
    const int chh  = seq >> 4;
    const int tid = threadIdx.x;
    const int t1 = 31 - pair;                   // heavy phase t
    const int t2 = pair;                        // light phase t

    const int px0 = (pxh << 11) + tid;
    const int px1 = px0 + 1024;
    const float bx0 = ((float)(px0 & 63) + 0.5f) * 0.03125f - 1.0f;
    const float by0 = ((float)(px0 >> 6) + 0.5f) * 0.03125f - 1.0f;
    const float bx1 = ((float)(px1 & 63) + 0.5f) * 0.03125f - 1.0f;
    const float by1 = ((float)(px1 >> 6) + 0.5f) * 0.03125f - 1.0f;

    const float2* cb = cum + (size_t)b * (LN * HWn);
    // frame k, channel-half chh: timg4 + ((b*32+k)*2 + chh)*4096
    const float4* fb = timg4 + ((size_t)b * 64 + chh) * 4096;  // + k*8192

    float4 st[4];                               // reg-staged next frame
#pragma unroll
    for (int j = 0; j < 4; ++j) st[j] = fb[j * 1024 + tid];    // frame 0

    float acc0[8] = {0}, acc1[8] = {0};
    float2 ct0 = make_float2(0.f, 0.f), ct1 = ct0;

    for (int i = 0; i < 33; ++i) {
        const bool ph2 = (i > t1);
        const int k = ph2 ? (i - t1 - 1) : i;
        const int t = ph2 ? t2 : t1;

        __syncthreads();                        // (A) all reads of sbuf done
#pragma unroll
        for (int j = 0; j < 4; ++j)             // frame i -> LDS (1KB/wave/st)
            sbuf[j * 1024 + tid] = st[j];
        __syncthreads();                        // (B) sbuf = frame k, visible

        if (i < 32) {                           // prefetch next frame -> regs
            const int kn = (i + 1 > t1) ? (i - t1) : (i + 1);
            const float4* src = fb + (size_t)kn * 8192;
#pragma unroll
            for (int j = 0; j < 4; ++j) st[j] = src[j * 1024 + tid];
        }

        if (k == 0) {                           // phase start
            ct0 = cb[t * HWn + px0];
            ct1 = cb[t * HWn + px1];
#pragma unroll
            for (int c = 0; c < 8; ++c) { acc0[c] = 0.f; acc1[c] = 0.f; }
        }
        const float2 ck0 = cb[k * HWn + px0];
        const float2 ck1 = cb[k * HWn + px1];
        px_step(sbuf, ct0, ck0, bx0, by0, acc0);
        px_step(sbuf, ct1, ck1, bx1, by1, acc1);

        if (k == t) {                           // phase end: write out
            float* op = out + ((size_t)(b * LN + t) * CN + chh * 8) * HWn;
#pragma unroll
            for (int c = 0; c < 8; ++c) {
                op[c * HWn + px0] = acc0[c];
                op[c * HWn + px1] = acc1[c];
            }
        }
    }
}

// ---------------------------------------------------------------------------
// Fallback (ws too small): direct fp32 gather (proven R1 kernel).
// ---------------------------------------------------------------------------
__global__ __launch_bounds__(256) void gsps_slow(
        const float* __restrict__ flows,
        const float* __restrict__ img,
        float* __restrict__ out) {
    const int bi = blockIdx.x;
    const int tile = bi & 15;
    const int rest = bi >> 4;
    const int t = 31 - (rest & 31);
    const int b = rest >> 5;
    const int p = (tile << 8) + threadIdx.x;
    const int h = p >> 6, w = p & 63;
    const float base_x = ((float)w + 0.5f) * 0.03125f - 1.0f;
    const float base_y = ((float)h + 0.5f) * 0.03125f - 1.0f;
    const float* fl = flows + (size_t)b * (LN * 2 * HWn) + p;

    float ctx = 0.f, cty = 0.f;
    for (int j = 0; j <= t; ++j) { ctx += fl[(2*j)*HWn]; cty += fl[(2*j+1)*HWn]; }

    float acc[16];
#pragma unroll
    for (int c = 0; c < 16; ++c) acc[c] = 0.f;

    float ckx = 0.f, cky = 0.f;
    for (int k = 0; k <= t; ++k) {
        ckx += fl[(2*k)*HWn]; cky += fl[(2*k+1)*HWn];
        float vx = (base_x + (ctx - ckx)) + 1.0f;
        float vy = (base_y + (cty - cky)) + 1.0f;
        float mx = vx - 2.0f * floorf(vx * 0.5f);
        float my = vy - 2.0f * floorf(vy * 0.5f);
        const float ix = ((mx - 1.0f) + 1.0f) * 32.0f - 0.5f;
        const float iy = ((my - 1.0f) + 1.0f) * 32.0f - 0.5f;
        const float x0f = floorf(ix), y0f = floorf(iy);
        const int x0 = (int)x0f, y0 = (int)y0f;
        const float wx1 = ix - x0f, wy1 = iy - y0f;
        const float wx0 = 1.0f - wx1, wy0 = 1.0f - wy1;
        const int x1 = x0 + 1, y1 = y0 + 1;
        const float fx0 = (x0 >= 0) ? 1.0f : 0.0f;
        const float fx1 = (x1 <= 63) ? 1.0f : 0.0f;
        const float fy0 = (y0 >= 0) ? 1.0f : 0.0f;
        const float fy1 = (y1 <= 63) ? 1.0f : 0.0f;
        const int x0c = (x0 < 0) ? 0 : x0, x1c = (x1 > 63) ? 63 : x1;
        const int y0c = (y0 < 0) ? 0 : y0, y1c = (y1 > 63) ? 63 : y1;
        const float w00 = (wx0*wy0)*(fx0*fy0), w10 = (wx1*wy0)*(fx1*fy0);
        const float w01 = (wx0*wy1)*(fx0*fy1), w11 = (wx1*wy1)*(fx1*fy1);
        const float* frm = img + (size_t)(b * LN + k) * FRAME;
        const int i00 = (y0c<<6)+x0c, i10 = (y0c<<6)+x1c;
        const int i01 = (y1c<<6)+x0c, i11 = (y1c<<6)+x1c;
#pragma unroll
        for (int c = 0; c < 16; ++c) {
            const float* pl = frm + c * HWn;
            acc[c] += ((w00*pl[i00] + w10*pl[i10]) + w01*pl[i01]) + w11*pl[i11];
        }
    }
    float* op = out + (size_t)(b * LN + t) * FRAME + p;
#pragma unroll
    for (int c = 0; c < 16; ++c) op[c * HWn] = acc[c];
}

extern "C" void kernel_launch(void* const* d_in, const int* in_sizes, int n_in,
                              void* d_out, int out_size, void* d_ws, size_t ws_size,
                              hipStream_t stream) {
    const float* flows  = (const float*)d_in[0];   // [4,32,2,64,64] f32
    const float* images = (const float*)d_in[1];   // [4,32,16,64,64] f32
    float* out = (float*)d_out;                    // [4,32,16,64,64] f32

    if (ws_size >= TIMG_BYTES + CUM_BYTES) {
        float4* timg = (float4*)d_ws;
        float2* cumw = (float2*)((char*)d_ws + TIMG_BYTES);
        prep_timg<<<BN * LN * 16, 256, 0, stream>>>(images, timg);
        prep_cum<<<BN * 16, 256, 0, stream>>>(flows, cumw);
        gsps_lds<<<256, 1024, 0, stream>>>(cumw, timg, out);
    } else {
        gsps_slow<<<BN * LN * 16, 256, 0, stream>>>(flows, images, out);
    }
}

// Round 8
// 89.766 us; speedup vs baseline: 2.1506x; 2.1506x over previous
//
#include <hip/hip_runtime.h>

// GridSamplePScan: out[b,t,c] = sum_{k<=t} bilinear(images[b,k,c], wrap(base + cum_t - cum_k))
// B=4, L=32, C=16, H=W=64, fp32 in/out.
//
// R7: LDS-staged gather via global_load_lds + __syncthreads-only fencing.
//   R6 post-mortem: reg-staging (st[4] float4 across px_steps) spilled ->
//   452 MB scratch WRITE traffic, 189 us. Fix: DMA staging (no VGPRs),
//   2x64KB LDS double buffer. Per iter: sync -> issue STAGE(i+1 -> buf^1)
//   -> compute(i) from buf. __syncthreads drains vmcnt(0) at the NEXT
//   barrier, i.e. after a full compute phase -> latency hidden, race-free
//   with purely standard semantics (no raw s_barrier: R3-R5 lesson).
//   px math bit-identical to the R2/R6 kernels (passed, absmax 0.0625).

constexpr int BN = 4, LN = 32, CN = 16, HWn = 4096;
constexpr int FRAME = CN * HWn;
constexpr size_t TIMG_BYTES = (size_t)BN * LN * HWn * CN * 2;  // 16 MB fp16
constexpr size_t CUM_BYTES  = (size_t)BN * LN * HWn * 2 * 4;   // 4 MB f32

// ---------------------------------------------------------------------------
// images fp32 [B,L,C,H,W] -> fp16 [B*L][chhalf(2)][4096 px][8ch] (16B cells)
// ---------------------------------------------------------------------------
__global__ __launch_bounds__(256) void prep_timg(
        const float* __restrict__ img, float4* __restrict__ timg) {
    const int bi = blockIdx.x, tile = bi & 15, f = bi >> 4;   // f = b*L + l
    const int p = (tile << 8) + threadIdx.x;
    const float* src = img + (size_t)f * FRAME + p;
#pragma unroll
    for (int g = 0; g < 2; ++g) {
        union { float4 f4; _Float16 h[8]; } cell;
#pragma unroll
        for (int j = 0; j < 8; ++j)
            cell.h[j] = (_Float16)src[(g * 8 + j) * HWn];     // coalesced
        timg[((size_t)f * 2 + g) * HWn + p] = cell.f4;        // 16B/lane
    }
}

// ---------------------------------------------------------------------------
__global__ __launch_bounds__(256) void prep_cum(
        const float* __restrict__ flows, float2* __restrict__ cum) {
    const int b = blockIdx.x >> 4;
    const int p = ((blockIdx.x & 15) << 8) + threadIdx.x;
    const float* fl = flows + (size_t)b * (LN * 2 * HWn) + p;
    float cx = 0.f, cy = 0.f;
    for (int l = 0; l < LN; ++l) {              // ascending == jnp.cumsum
        cx += fl[(2 * l) * HWn];
        cy += fl[(2 * l + 1) * HWn];
        cum[(size_t)(b * LN + l) * HWn + p] = make_float2(cx, cy);
    }
}

// ---------------------------------------------------------------------------
// Bilinear sample of one pixel from the LDS-resident 8-channel frame.
// Math bit-identical to the reference (and the passing R2/R6 kernels).
// ---------------------------------------------------------------------------
__device__ __forceinline__ void px_step(const float4* __restrict__ fr,
                                        float2 ct, float2 ck,
                                        float bx, float by,
                                        float* __restrict__ acc) {
    float vx = (bx + (ct.x - ck.x)) + 1.0f;     // (base + rel) + 1, ref order
    float vy = (by + (ct.y - ck.y)) + 1.0f;
    float mx = vx - 2.0f * floorf(vx * 0.5f);   // == jnp.mod(v,2) bitwise
    float my = vy - 2.0f * floorf(vy * 0.5f);
    float ix = ((mx - 1.0f) + 1.0f) * 32.0f - 0.5f;  // keep ref's -1/+1 trip
    float iy = ((my - 1.0f) + 1.0f) * 32.0f - 0.5f;
    float xf = floorf(ix), yf = floorf(iy);
    int x0 = (int)xf, y0 = (int)yf;             // [-1, 63]
    float wx1 = ix - xf, wy1 = iy - yf;
    float wx0 = 1.0f - wx1, wy0 = 1.0f - wy1;
    wx0 = (x0 >= 0) ? wx0 : 0.0f;               // zero-pad outside image
    wx1 = (x0 <= 62) ? wx1 : 0.0f;
    wy0 = (y0 >= 0) ? wy0 : 0.0f;
    wy1 = (y0 <= 62) ? wy1 : 0.0f;
    const int x0c = max(x0, 0), y0c = max(y0, 0);
    const int x1c = min(x0 + 1, 63), y1c = min(y0 + 1, 63);
    const float w00 = wx0 * wy0, w10 = wx1 * wy0;
    const float w01 = wx0 * wy1, w11 = wx1 * wy1;
    union { float4 f4; _Float16 h[8]; } g00, g10, g01, g11;
    g00.f4 = fr[(y0c << 6) + x0c];              // ds_read_b128
    g10.f4 = fr[(y0c << 6) + x1c];
    g01.f4 = fr[(y1c << 6) + x0c];
    g11.f4 = fr[(y1c << 6) + x1c];
#pragma unroll
    for (int c = 0; c < 8; ++c)                 // v_fma_mix_f32: f32 accum
        acc[c] += ((w00 * (float)g00.h[c] + w10 * (float)g10.h[c])
                   + w01 * (float)g01.h[c]) + w11 * (float)g11.h[c];
}

// ---------------------------------------------------------------------------
__global__ __launch_bounds__(1024, 4) void gsps_lds(
        const float2* __restrict__ cum,
        const char* __restrict__ timg,
        float* __restrict__ out) {
    extern __shared__ char smem[];              // 2 x 64KB double buffer
    const int bid = blockIdx.x;                 // 256 blocks
    const int xs  = bid & 7;                    // XCD slot (round-robin)
    const int b   = xs >> 1;                    // batch pinned to XCD pair
    const int pxh = xs & 1;
    const int seq = bid >> 3;
    const int pair = seq & 15;
    const int chh  = seq >> 4;
    const int tid = threadIdx.x;
    const int t1 = 31 - pair;                   // heavy phase t
    const int t2 = pair;                        // light phase t

    const int px0 = (pxh << 11) + tid;
    const int px1 = px0 + 1024;
    const float bx0 = ((float)(px0 & 63) + 0.5f) * 0.03125f - 1.0f;
    const float by0 = ((float)(px0 >> 6) + 0.5f) * 0.03125f - 1.0f;
    const float bx1 = ((float)(px1 & 63) + 0.5f) * 0.03125f - 1.0f;
    const float by1 = ((float)(px1 >> 6) + 0.5f) * 0.03125f - 1.0f;

    const float2* cb = cum + (size_t)b * (LN * HWn);
    // frame k, channel-half chh byte offset: ((b*32+k)*2 + chh) * 65536
    const size_t chunk0 = (((size_t)b * LN * 2) + chh) << 16;
    const unsigned wbase = (unsigned)(tid & ~63) << 4;   // wave-uniform *1024

    // wave-uniform LDS base + lane*16 (HW rule); identity mapping to global
#define STAGE(KK, BUF) do {                                                   \
    const char* gsrc = timg + chunk0 + ((size_t)(KK) << 17);                  \
    _Pragma("unroll")                                                         \
    for (int j = 0; j < 4; ++j) {                                             \
        __builtin_amdgcn_global_load_lds(                                     \
            (const __attribute__((address_space(1))) void*)                  \
                (gsrc + j * 16384 + tid * 16),                                \
            (__attribute__((address_space(3))) void*)                        \
                (smem + ((BUF) << 16) + wbase + j * 16384),                   \
            16, 0, 0);                                                        \
    }                                                                         \
} while (0)

    float acc0[8] = {0}, acc1[8] = {0};
    float2 ct0 = make_float2(0.f, 0.f), ct1 = ct0;
    float2 ckp0 = cb[px0], ckp1 = cb[px1];      // ck prefetch for iter 0 (k=0)

    STAGE(0, 0);                                // prologue: frame 0 -> buf0

    for (int i = 0; i < 33; ++i) {
        const bool ph2 = (i > t1);
        const int k = ph2 ? (i - t1 - 1) : i;
        const int t = ph2 ? t2 : t1;

        // drains vmcnt(0): STAGE(i) complete; also fences buf^1 readers
        __syncthreads();
        if (i < 32) {                           // issue next-frame DMA now;
            const int kn = (i + 1 > t1) ? (i - t1) : (i + 1);
            STAGE(kn, (i + 1) & 1);             // drained at NEXT barrier
        }

        const float2 ck0 = ckp0, ck1 = ckp1;
        if (i < 32) {                           // prefetch next ck pair
            const int kn = (i + 1 > t1) ? (i - t1) : (i + 1);
            ckp0 = cb[kn * HWn + px0];
            ckp1 = cb[kn * HWn + px1];
        }
        if (k == 0) {                           // phase start
            ct0 = cb[t * HWn + px0];
            ct1 = cb[t * HWn + px1];
#pragma unroll
            for (int c = 0; c < 8; ++c) { acc0[c] = 0.f; acc1[c] = 0.f; }
        }
        const float4* fr = (const float4*)(smem + ((i & 1) << 16));
        px_step(fr, ct0, ck0, bx0, by0, acc0);
        px_step(fr, ct1, ck1, bx1, by1, acc1);

        if (k == t) {                           // phase end: write out
            float* op = out + ((size_t)(b * LN + t) * CN + chh * 8) * HWn;
#pragma unroll
            for (int c = 0; c < 8; ++c) {
                op[c * HWn + px0] = acc0[c];
                op[c * HWn + px1] = acc1[c];
            }
        }
    }
#undef STAGE
}

// ---------------------------------------------------------------------------
// Fallback (ws too small / attr fails): direct fp32 gather (proven R1 kernel).
// ---------------------------------------------------------------------------
__global__ __launch_bounds__(256) void gsps_slow(
        const float* __restrict__ flows,
        const float* __restrict__ img,
        float* __restrict__ out) {
    const int bi = blockIdx.x;
    const int tile = bi & 15;
    const int rest = bi >> 4;
    const int t = 31 - (rest & 31);
    const int b = rest >> 5;
    const int p = (tile << 8) + threadIdx.x;
    const int h = p >> 6, w = p & 63;
    const float base_x = ((float)w + 0.5f) * 0.03125f - 1.0f;
    const float base_y = ((float)h + 0.5f) * 0.03125f - 1.0f;
    const float* fl = flows + (size_t)b * (LN * 2 * HWn) + p;

    float ctx = 0.f, cty = 0.f;
    for (int j = 0; j <= t; ++j) { ctx += fl[(2*j)*HWn]; cty += fl[(2*j+1)*HWn]; }

    float acc[16];
#pragma unroll
    for (int c = 0; c < 16; ++c) acc[c] = 0.f;

    float ckx = 0.f, cky = 0.f;
    for (int k = 0; k <= t; ++k) {
        ckx += fl[(2*k)*HWn]; cky += fl[(2*k+1)*HWn];
        float vx = (base_x + (ctx - ckx)) + 1.0f;
        float vy = (base_y + (cty - cky)) + 1.0f;
        float mx = vx - 2.0f * floorf(vx * 0.5f);
        float my = vy - 2.0f * floorf(vy * 0.5f);
        const float ix = ((mx - 1.0f) + 1.0f) * 32.0f - 0.5f;
        const float iy = ((my - 1.0f) + 1.0f) * 32.0f - 0.5f;
        const float x0f = floorf(ix), y0f = floorf(iy);
        const int x0 = (int)x0f, y0 = (int)y0f;
        const float wx1 = ix - x0f, wy1 = iy - y0f;
        const float wx0 = 1.0f - wx1, wy0 = 1.0f - wy1;
        const int x1 = x0 + 1, y1 = y0 + 1;
        const float fx0 = (x0 >= 0) ? 1.0f : 0.0f;
        const float fx1 = (x1 <= 63) ? 1.0f : 0.0f;
        const float fy0 = (y0 >= 0) ? 1.0f : 0.0f;
        const float fy1 = (y1 <= 63) ? 1.0f : 0.0f;
        const int x0c = (x0 < 0) ? 0 : x0, x1c = (x1 > 63) ? 63 : x1;
        const int y0c = (y0 < 0) ? 0 : y0, y1c = (y1 > 63) ? 63 : y1;
        const float w00 = (wx0*wy0)*(fx0*fy0), w10 = (wx1*wy0)*(fx1*fy0);
        const float w01 = (wx0*wy1)*(fx0*fy1), w11 = (wx1*wy1)*(fx1*fy1);
        const float* frm = img + (size_t)(b * LN + k) * FRAME;
        const int i00 = (y0c<<6)+x0c, i10 = (y0c<<6)+x1c;
        const int i01 = (y1c<<6)+x0c, i11 = (y1c<<6)+x1c;
#pragma unroll
        for (int c = 0; c < 16; ++c) {
            const float* pl = frm + c * HWn;
            acc[c] += ((w00*pl[i00] + w10*pl[i10]) + w01*pl[i01]) + w11*pl[i11];
        }
    }
    float* op = out + (size_t)(b * LN + t) * FRAME + p;
#pragma unroll
    for (int c = 0; c < 16; ++c) op[c * HWn] = acc[c];
}

extern "C" void kernel_launch(void* const* d_in, const int* in_sizes, int n_in,
                              void* d_out, int out_size, void* d_ws, size_t ws_size,
                              hipStream_t stream) {
    const float* flows  = (const float*)d_in[0];   // [4,32,2,64,64] f32
    const float* images = (const float*)d_in[1];   // [4,32,16,64,64] f32
    float* out = (float*)d_out;                    // [4,32,16,64,64] f32

    bool fast = (ws_size >= TIMG_BYTES + CUM_BYTES);
    if (fast) {
        hipError_t e = hipFuncSetAttribute(
            reinterpret_cast<const void*>(&gsps_lds),
            hipFuncAttributeMaxDynamicSharedMemorySize, 131072);
        if (e != hipSuccess) fast = false;
    }
    if (fast) {
        float4* timg = (float4*)d_ws;
        float2* cumw = (float2*)((char*)d_ws + TIMG_BYTES);
        prep_timg<<<BN * LN * 16, 256, 0, stream>>>(images, timg);
        prep_cum<<<BN * 16, 256, 0, stream>>>(flows, cumw);
        gsps_lds<<<256, 1024, 131072, stream>>>(cumw, (const char*)timg, out);
    } else {
        gsps_slow<<<BN * LN * 16, 256, 0, stream>>>(flows, images, out);
    }
}